// Round 1
// baseline (4102.465 us; speedup 1.0000x reference)
//
#include <hip/hip_runtime.h>
#include <math.h>

// ---------------- problem constants ----------------
#define POSE_ROWS 144
#define NF 135          // IN_F
#define DD 512
#define KQ 10
#define DCTN 34         // DCT_N == VL
#define INN 120
#define OUTN 24
#define VN 87           // IN_N - VL + 1
#define BATCH 256
#define BN_SCALE 0.9999950000374997f  // 1/sqrt(1+1e-5)

// ---------------- DCT matrix generation (orthonormal DCT-II; inverse == transpose) ----------
__global__ void dct_gen(float* __restrict__ dct) {
    int idx = blockIdx.x * 64 + threadIdx.x;
    if (idx >= DCTN * DCTN) return;
    int k = idx / DCTN, i = idx % DCTN;
    double w = (k == 0) ? sqrt(1.0 / DCTN) : sqrt(2.0 / DCTN);
    double v = w * cos(3.14159265358979323846 * (i + 0.5) * k / (double)DCTN);
    dct[idx] = (float)v;
}

// ---------------- weight repack: w[O][I][H] -> wp[k=h*I+i][O] ----------------
__global__ void pack_w(const float* __restrict__ w, float* __restrict__ wp, int I, int H, int O) {
    long long idx = (long long)blockIdx.x * 256 + threadIdx.x;
    long long tot = (long long)I * H * O;
    if (idx >= tot) return;
    int o = (int)(idx % O);
    long long k = idx / O;
    int i = (int)(k % I);
    int h = (int)(k / I);
    wp[idx] = w[(long long)o * I * H + (long long)i * H + h];
}

// ---------------- generic tiled f32 GEMM ----------------
// C[bz][m,n] = epilogue( sum_k Arow(m)[k] * B[bz][k,n] )
// A row offset = (m/rows_per_b)*sAb + (m%rows_per_b)*sAr   (A not batched)
// B offset += bz*sBb ; C/resid offset += bz*sCb ; C is MxN row-major (ld=N)
__global__ __launch_bounds__(256) void gemm_f32(
    const float* __restrict__ A, const float* __restrict__ B, float* __restrict__ C,
    int M, int N, int K,
    int rows_per_b, long long sAb, int sAr,
    long long sBb, long long sCb,
    float scale, int do_relu,
    const float* __restrict__ bias,
    const float* __restrict__ bn_g, const float* __restrict__ bn_beta, int bn_mrows,
    int do_tanh,
    const float* __restrict__ resid)
{
    const int bz = blockIdx.z;
    const float* Bb = B + (long long)bz * sBb;
    float* Cb = C + (long long)bz * sCb;

    const int m0 = blockIdx.y * 64;
    const int n0 = blockIdx.x * 64;
    const int tid = threadIdx.x;

    __shared__ float As[16][68];   // As[k][m], padded
    __shared__ float Bs[16][64];   // Bs[k][n]

    // A-load mapping: each thread owns one row, 4 consecutive k (scalar loads: rows may be 4B-aligned only)
    const int arow = tid >> 2;          // 0..63
    const int akq  = (tid & 3) * 4;     // 0,4,8,12
    const int am   = m0 + arow;
    const float* Arow = A;
    if (am < M) {
        long long off = (long long)(am / rows_per_b) * sAb + (long long)(am % rows_per_b) * sAr;
        Arow = A + off;
    }
    // B-load mapping: kk = tid/16, n = n0 + (tid%16)*4
    const int bkk = tid >> 4;
    const int bnq = (tid & 15) * 4;

    const int tx = (tid & 15) * 4;      // n sub-tile
    const int ty = (tid >> 4) * 4;      // m sub-tile

    float acc[4][4] = {};

    for (int k0 = 0; k0 < K; k0 += 16) {
        // A tile
        {
            float4 av = make_float4(0.f, 0.f, 0.f, 0.f);
            if (am < M) {
                int k = k0 + akq;
                if (k     < K) av.x = Arow[k];
                if (k + 1 < K) av.y = Arow[k + 1];
                if (k + 2 < K) av.z = Arow[k + 2];
                if (k + 3 < K) av.w = Arow[k + 3];
            }
            As[akq + 0][arow] = av.x;
            As[akq + 1][arow] = av.y;
            As[akq + 2][arow] = av.z;
            As[akq + 3][arow] = av.w;
        }
        // B tile
        {
            float4 bv = make_float4(0.f, 0.f, 0.f, 0.f);
            int k = k0 + bkk;
            int n = n0 + bnq;
            if (k < K) {
                const float* Brow = Bb + (long long)k * N + n;
                if (n + 3 < N) {
                    bv = *(const float4*)Brow;   // packed B rows are 16B-aligned for all our shapes
                } else {
                    if (n     < N) bv.x = Brow[0];
                    if (n + 1 < N) bv.y = Brow[1];
                    if (n + 2 < N) bv.z = Brow[2];
                }
            }
            *(float4*)&Bs[bkk][bnq] = bv;
        }
        __syncthreads();
        #pragma unroll
        for (int kk = 0; kk < 16; kk++) {
            float4 a = *(const float4*)&As[kk][ty];
            float4 b = *(const float4*)&Bs[kk][tx];
            float av[4] = {a.x, a.y, a.z, a.w};
            float bv[4] = {b.x, b.y, b.z, b.w};
            #pragma unroll
            for (int i = 0; i < 4; i++)
                #pragma unroll
                for (int j = 0; j < 4; j++)
                    acc[i][j] = fmaf(av[i], bv[j], acc[i][j]);
        }
        __syncthreads();
    }

    const float* Rb = resid ? (resid + (long long)bz * sCb) : nullptr;
    #pragma unroll
    for (int i = 0; i < 4; i++) {
        int m = m0 + ty + i;
        if (m >= M) continue;
        #pragma unroll
        for (int j = 0; j < 4; j++) {
            int n = n0 + tx + j;
            if (n >= N) continue;
            float v = acc[i][j] * scale;
            if (do_relu) v = fmaxf(v, 0.f);
            if (bias) v += bias[n];
            if (bn_g) {
                int r = m % bn_mrows;
                long long gi = (long long)r * N + n;
                v = bn_g[gi] * (v * BN_SCALE) + bn_beta[gi];
            }
            if (do_tanh) v = tanhf(v);
            long long ci = (long long)m * N + n;
            if (Rb) v += Rb[ci];
            Cb[ci] = v;
        }
    }
}

// ---------------- attention scores + normalize ----------------
// kf: (b, 87, 512) ; qf: (b, 512) ; att: (b, 87)
__global__ __launch_bounds__(256) void att_k(const float* __restrict__ kf, const float* __restrict__ qf,
                                             float* __restrict__ att) {
    int b = blockIdx.x;
    int tid = threadIdx.x;
    __shared__ float s[VN];
    __shared__ float red[4];
    __shared__ float ssum;
    float q0 = qf[b * DD + tid];
    float q1 = qf[b * DD + 256 + tid];
    const float* kb = kf + (long long)b * VN * DD;
    for (int v = 0; v < VN; v++) {
        float p = q0 * kb[v * DD + tid] + q1 * kb[v * DD + 256 + tid];
        for (int off = 32; off > 0; off >>= 1) p += __shfl_down(p, off);
        if ((tid & 63) == 0) red[tid >> 6] = p;
        __syncthreads();
        if (tid == 0) s[v] = red[0] + red[1] + red[2] + red[3] + 1e-15f;
        __syncthreads();
    }
    if (tid < 64) {
        float p2 = s[tid] + ((tid + 64) < VN ? s[tid + 64] : 0.f);
        for (int off = 32; off > 0; off >>= 1) p2 += __shfl_down(p2, off);
        if (tid == 0) ssum = p2;
    }
    __syncthreads();
    for (int v = tid; v < VN; v += 256) att[b * VN + v] = s[v] / ssum;
}

// ---------------- attention-weighted window sum: w34[b,t,f] = sum_v att[b,v]*poses[b,v+t,f] ----------------
__global__ void weighted_k(const float* __restrict__ poses, const float* __restrict__ att,
                           float* __restrict__ w34) {
    int t = blockIdx.x;   // 0..33
    int b = blockIdx.y;
    int f = threadIdx.x;  // 0..191
    if (f >= NF) return;
    const float* pb = poses + (long long)b * POSE_ROWS * NF + t * NF + f;
    const float* ab = att + b * VN;
    float acc = 0.f;
    for (int v = 0; v < VN; v++) acc += ab[v] * pb[v * NF];
    w34[(long long)b * DCTN * NF + t * NF + f] = acc;
}

// ---------------- build x = concat(dct_in, dct_att): x[b, f(135), kk(68)] ----------------
__global__ void build_x(const float* __restrict__ poses, const float* __restrict__ w34,
                        const float* __restrict__ dct, float* __restrict__ x) {
    int idx = blockIdx.x * 256 + threadIdx.x;
    if (idx >= BATCH * NF * 68) return;
    int kk = idx % 68;
    int f = (idx / 68) % NF;
    int b = idx / (68 * NF);
    float acc = 0.f;
    if (kk < DCTN) {
        const float* pb = poses + (long long)b * POSE_ROWS * NF;
        #pragma unroll
        for (int t = 0; t < DCTN; t++) {
            int row = (t < KQ) ? (INN - KQ + t) : (INN - 1);
            acc += dct[kk * DCTN + t] * pb[row * NF + f];
        }
    } else {
        int k2 = kk - DCTN;
        const float* wb = w34 + (long long)b * DCTN * NF + f;
        #pragma unroll
        for (int t = 0; t < DCTN; t++) acc += dct[k2 * DCTN + t] * wb[t * NF];
    }
    x[idx] = acc;
}

// ---------------- final IDCT + slice: preds[b,t(24),f] = sum_k dct[k][10+t] * yfin[b,f,k] ----------------
__global__ void idct_out(const float* __restrict__ yfin, const float* __restrict__ dct,
                         float* __restrict__ out) {
    int idx = blockIdx.x * 256 + threadIdx.x;
    if (idx >= BATCH * OUTN * NF) return;
    int f = idx % NF;
    int t = (idx / NF) % OUTN;
    int b = idx / (NF * OUTN);
    const float* yr = yfin + (long long)b * NF * 68 + f * 68;
    float acc = 0.f;
    #pragma unroll
    for (int k = 0; k < DCTN; k++) acc += dct[k * DCTN + (KQ + t)] * yr[k];
    out[idx] = acc;
}

// ---------------- host-side launch ----------------
extern "C" void kernel_launch(void* const* d_in, const int* in_sizes, int n_in,
                              void* d_out, int out_size, void* d_ws, size_t ws_size,
                              hipStream_t stream) {
    const float* poses   = (const float*)d_in[0];
    const float* qw1     = (const float*)d_in[1];
    const float* qw2     = (const float*)d_in[2];
    const float* kw1     = (const float*)d_in[3];
    const float* kw2     = (const float*)d_in[4];
    const float* gc1_att = (const float*)d_in[5];
    const float* gc1_w   = (const float*)d_in[6];
    const float* gc1_b   = (const float*)d_in[7];
    const float* bn1_g   = (const float*)d_in[8];
    const float* bn1_b   = (const float*)d_in[9];
    const float* gcb_att = (const float*)d_in[10];
    const float* gcb_w   = (const float*)d_in[11];
    const float* gcb_b   = (const float*)d_in[12];
    const float* gcb_g   = (const float*)d_in[13];
    const float* gcb_beta= (const float*)d_in[14];
    const float* gc7_att = (const float*)d_in[15];
    const float* gc7_w   = (const float*)d_in[16];
    const float* gc7_b   = (const float*)d_in[17];
    float* out = (float*)d_out;
    float* w = (float*)d_ws;

    // workspace layout (floats); phase-A buffers aliased over y/z/h region
    float* dct  = w;                          // 1156  (pad 1280)
    float* att  = w + 1280;                   // 22272 (pad 22528)
    float* w34  = w + 23808;                  // 256*34*135 = 1175040
    float* x    = w + 1198848;                // 256*135*68 = 2350080
    float* y    = w + 3548928;                // 256*135*512 = 17694720
    float* z    = w + 21243648;               // 17694720
    float* h    = w + 38938368;               // 17694720   (total 56633088 floats = 226.5 MB)
    // phase A aliases (dead before y/z/h first written)
    float* k1p  = y;                          // 810*512
    float* q1p  = y + 414720;
    float* k2p  = y + 829440;                 // 2560*512
    float* q2p  = y + 2140160;
    float* r1k  = y + 3450880;                // 256*91*512 = 11927552
    float* r1q  = y + 15378432;               // 256*5*512
    float* kf   = y + 16033792;               // 256*87*512 = 11403264
    float* qf   = y + 27437056;               // 256*512

    auto g64 = [](int M, int N, int bz) { return dim3((N + 63) / 64, (M + 63) / 64, bz); };

    dct_gen<<<19, 64, 0, stream>>>(dct);
    pack_w<<<(810 * 512 + 255) / 256, 256, 0, stream>>>(kw1, k1p, 135, 6, 512);
    pack_w<<<(810 * 512 + 255) / 256, 256, 0, stream>>>(qw1, q1p, 135, 6, 512);
    pack_w<<<(2560 * 512 + 255) / 256, 256, 0, stream>>>(kw2, k2p, 512, 5, 512);
    pack_w<<<(2560 * 512 + 255) / 256, 256, 0, stream>>>(qw2, q2p, 512, 5, 512);

    // conv1 key: M=256*91, K=810 (A rows = poses windows, contiguous 810 floats)
    gemm_f32<<<g64(23296, 512, 1), 256, 0, stream>>>(poses, k1p, r1k, 23296, 512, 810,
        91, (long long)POSE_ROWS * NF, NF, 0LL, 0LL, 1e-3f, 1, nullptr, nullptr, nullptr, 0, 0, nullptr);
    // conv1 qry: rows start at t=110
    gemm_f32<<<g64(1280, 512, 1), 256, 0, stream>>>(poses + (INN - KQ) * NF, q1p, r1q, 1280, 512, 810,
        5, (long long)POSE_ROWS * NF, NF, 0LL, 0LL, 1e-3f, 1, nullptr, nullptr, nullptr, 0, 0, nullptr);
    // conv2 key: M=256*87, K=2560
    gemm_f32<<<g64(22272, 512, 1), 256, 0, stream>>>(r1k, k2p, kf, 22272, 512, 2560,
        87, 91LL * 512, 512, 0LL, 0LL, 1.f, 1, nullptr, nullptr, nullptr, 0, 0, nullptr);
    // conv2 qry: M=256, K=2560
    gemm_f32<<<g64(256, 512, 1), 256, 0, stream>>>(r1q, q2p, qf, 256, 512, 2560,
        1, 5LL * 512, 512, 0LL, 0LL, 1.f, 1, nullptr, nullptr, nullptr, 0, 0, nullptr);

    att_k<<<BATCH, 256, 0, stream>>>(kf, qf, att);
    weighted_k<<<dim3(DCTN, BATCH), 192, 0, stream>>>(poses, att, w34);
    build_x<<<(BATCH * NF * 68 + 255) / 256, 256, 0, stream>>>(poses, w34, dct, x);

    // gc1: mix-first (68-wide), then 68->512 GEMM with bias+bn+tanh
    gemm_f32<<<g64(135, 68, BATCH), 256, 0, stream>>>(gc1_att, x, z, 135, 68, 135,
        135, 0LL, 135, 135LL * 68, 135LL * 68, 1.f, 0, nullptr, nullptr, nullptr, 0, 0, nullptr);
    gemm_f32<<<g64(34560, 512, 1), 256, 0, stream>>>(z, gc1_w, y, 34560, 512, 68,
        34560, 0LL, 68, 0LL, 0LL, 1.f, 0, gc1_b, bn1_g, bn1_b, 135, 1, nullptr);

    // residual GCN blocks
    for (int i = 0; i < 2; i++) {
        int L0 = 2 * i, L1 = 2 * i + 1;
        // layer L0: mix(y)->z ; (z@W) -> h  with bias+bn+tanh
        gemm_f32<<<g64(135, 512, BATCH), 256, 0, stream>>>(gcb_att + L0 * 18225, y, z, 135, 512, 135,
            135, 0LL, 135, 135LL * 512, 135LL * 512, 1.f, 0, nullptr, nullptr, nullptr, 0, 0, nullptr);
        gemm_f32<<<g64(34560, 512, 1), 256, 0, stream>>>(z, gcb_w + L0 * 262144, h, 34560, 512, 512,
            34560, 0LL, 512, 0LL, 0LL, 1.f, 0, gcb_b + L0 * 512, gcb_g + L0 * 69120, gcb_beta + L0 * 69120, 135, 1, nullptr);
        // layer L1: mix(h)->z ; (z@W) + residual(y) -> y
        gemm_f32<<<g64(135, 512, BATCH), 256, 0, stream>>>(gcb_att + L1 * 18225, h, z, 135, 512, 135,
            135, 0LL, 135, 135LL * 512, 135LL * 512, 1.f, 0, nullptr, nullptr, nullptr, 0, 0, nullptr);
        gemm_f32<<<g64(34560, 512, 1), 256, 0, stream>>>(z, gcb_w + L1 * 262144, y, 34560, 512, 512,
            34560, 0LL, 512, 0LL, 0LL, 1.f, 0, gcb_b + L1 * 512, gcb_g + L1 * 69120, gcb_beta + L1 * 69120, 135, 1, y);
    }

    // gc7: (y@W 512->68) -> z ; mix + bias + x-residual -> h
    gemm_f32<<<g64(34560, 68, 1), 256, 0, stream>>>(y, gc7_w, z, 34560, 68, 512,
        34560, 0LL, 512, 0LL, 0LL, 1.f, 0, nullptr, nullptr, nullptr, 0, 0, nullptr);
    gemm_f32<<<g64(135, 68, BATCH), 256, 0, stream>>>(gc7_att, z, h, 135, 68, 135,
        135, 0LL, 135, 135LL * 68, 135LL * 68, 1.f, 0, gc7_b, nullptr, nullptr, 0, 0, x);

    idct_out<<<(BATCH * OUTN * NF + 255) / 256, 256, 0, stream>>>(h, dct, out);
}

// Round 2
// 1633.827 us; speedup vs baseline: 2.5110x; 2.5110x over previous
//
#include <hip/hip_runtime.h>
#include <math.h>

// ---------------- problem constants ----------------
#define POSE_ROWS 144
#define NF 135
#define DD 512
#define KQ 10
#define DCTN 34
#define INN 120
#define OUTN 24
#define VN 87
#define BATCH 256
#define RP 34816              // padded row dim: 256 * 136
#define NODEP 136
#define BN_SCALE 0.9999950000374997f

typedef __attribute__((ext_vector_type(8))) short short8;
typedef __attribute__((ext_vector_type(4))) float floatx4;

static __device__ __forceinline__ ushort f2bf(float f) {
    unsigned u = __builtin_bit_cast(unsigned, f);
    u = (u + 0x7FFFu + ((u >> 16) & 1u)) >> 16;
    return (ushort)u;
}

// ---------------- DCT matrix (orthonormal DCT-II; inverse == transpose) ----------
__global__ void dct_gen(float* __restrict__ dct) {
    int idx = blockIdx.x * 64 + threadIdx.x;
    if (idx >= DCTN * DCTN) return;
    int k = idx / DCTN, i = idx % DCTN;
    double w = (k == 0) ? sqrt(1.0 / DCTN) : sqrt(2.0 / DCTN);
    dct[idx] = (float)(w * cos(3.14159265358979323846 * (i + 0.5) * k / (double)DCTN));
}

// ---------------- poses -> bf16, *1e-3, inner dim padded 135->136 ----------------
__global__ void cvt_poses(const float* __restrict__ poses, ushort* __restrict__ pb) {
    int idx = blockIdx.x * 256 + threadIdx.x;
    if (idx >= BATCH * POSE_ROWS * NODEP) return;
    int i = idx % NODEP;
    int row = (idx / NODEP) % POSE_ROWS;
    int b = idx / (NODEP * POSE_ROWS);
    float v = (i < NF) ? poses[((long long)b * POSE_ROWS + row) * NF + i] * 1e-3f : 0.f;
    pb[idx] = f2bf(v);
}

// ---------------- conv weights: w[O][I][H] -> wt[o][k=h*padI+i] bf16 ----------------
__global__ void pack_conv(const float* __restrict__ w, ushort* __restrict__ wt,
                          int I, int H, int padI, int KP, int total) {
    int idx = blockIdx.x * 256 + threadIdx.x;
    if (idx >= total) return;
    int n = idx / KP, k = idx % KP;
    int h = k / padI, i = k % padI;
    float v = (i < I) ? w[((long long)n * I + i) * H + h] : 0.f;
    wt[idx] = f2bf(v);
}

// ---------------- W[k][n] f32 -> Wt[n][k] bf16, k padded to KP ----------------
__global__ void transpose_cvt(const float* __restrict__ w, ushort* __restrict__ wt,
                              int Kd, int Nd, int KP, int total) {
    int idx = blockIdx.x * 256 + threadIdx.x;
    if (idx >= total) return;
    int n = idx / KP, k = idx % KP;
    float v = (k < Kd) ? w[(long long)k * Nd + n] : 0.f;
    wt[idx] = f2bf(v);
}

// ---------------- att f32 [rows][cols] -> bf16 [rows][colsP] zero-padded ----------------
__global__ void cvt_pad_rows(const float* __restrict__ a, ushort* __restrict__ o,
                             int rows, int cols, int colsP, int total) {
    int idx = blockIdx.x * 256 + threadIdx.x;
    if (idx >= total) return;
    int r = idx / colsP, c = idx % colsP;
    o[idx] = f2bf(c < cols ? a[(long long)r * cols + c] : 0.f);
}

// ---------------- generic NT MFMA GEMM ----------------
// C[m,n] = epi( sum_k A[m,k] * Bt[n,k] )
// A row off = (m/rpbA)*sAw + (m%rpbA)*sAr + bz*sAbz ; Bt row off = n*sBr
// C addr   = bz*sCbz + m*sCm + n*sCn   (same map for C16 and resid)
template<int BM, int BN>
__global__ __launch_bounds__(256) void gemm_mfma(
    const ushort* __restrict__ A, const ushort* __restrict__ Bt,
    int M, int N, int K,
    int rpbA, long long sAw, long long sAr, long long sAbz,
    long long sBr,
    float* __restrict__ C, ushort* __restrict__ C16,
    long long sCbz, long long sCm, long long sCn,
    int do_relu, const float* __restrict__ bias, int bias_mode,
    const float* __restrict__ bn_g, const float* __restrict__ bn_b,
    int do_tanh, const float* __restrict__ resid)
{
    constexpr int LDK = 40;                 // 32 + 8 pad (80 B rows, 16B-aligned)
    __shared__ ushort As[BM * LDK];
    __shared__ ushort Bs[BN * LDK];

    const int tid = threadIdx.x;
    const int bz = blockIdx.z;
    const int m0 = blockIdx.y * BM;
    const int n0 = blockIdx.x * BN;
    const int lane = tid & 63;
    const int w = tid >> 6;
    const int wm = (w >> 1) * (BM / 2);
    const int wn = (w & 1) * (BN / 2);
    constexpr int SM = BM / 32, SN = BN / 32;

    floatx4 acc[SM][SN];
    #pragma unroll
    for (int i = 0; i < SM; i++)
        #pragma unroll
        for (int j = 0; j < SN; j++)
            acc[i][j] = (floatx4){0.f, 0.f, 0.f, 0.f};

    const int srow = tid >> 2;
    const int skq = (tid & 3) * 8;

    long long abase[BM / 64];
    #pragma unroll
    for (int it = 0; it < BM / 64; it++) {
        int m = m0 + it * 64 + srow;
        abase[it] = (m < M)
            ? (long long)(m / rpbA) * sAw + (long long)(m % rpbA) * sAr + (long long)bz * sAbz
            : -1LL;
    }
    long long bbase[BN / 64];
    #pragma unroll
    for (int it = 0; it < BN / 64; it++) {
        int n = n0 + it * 64 + srow;
        bbase[it] = (n < N) ? (long long)n * sBr : -1LL;
    }

    for (int k0 = 0; k0 < K; k0 += 32) {
        int k = k0 + skq;
        #pragma unroll
        for (int it = 0; it < BM / 64; it++) {
            uint4 v4 = make_uint4(0u, 0u, 0u, 0u);
            if (abase[it] >= 0 && k < K) {
                const ushort* p = A + abase[it] + k;
                if (k + 8 <= K) {
                    v4 = *(const uint4*)p;
                } else {
                    union { uint4 u; ushort s[8]; } t; t.u = make_uint4(0u,0u,0u,0u);
                    int lim = K - k;
                    for (int j = 0; j < 8; j++) if (j < lim) t.s[j] = p[j];
                    v4 = t.u;
                }
            }
            *(uint4*)&As[(it * 64 + srow) * LDK + skq] = v4;
        }
        #pragma unroll
        for (int it = 0; it < BN / 64; it++) {
            uint4 v4 = make_uint4(0u, 0u, 0u, 0u);
            if (bbase[it] >= 0 && k < K) {
                const ushort* p = Bt + bbase[it] + k;
                if (k + 8 <= K) {
                    v4 = *(const uint4*)p;
                } else {
                    union { uint4 u; ushort s[8]; } t; t.u = make_uint4(0u,0u,0u,0u);
                    int lim = K - k;
                    for (int j = 0; j < 8; j++) if (j < lim) t.s[j] = p[j];
                    v4 = t.u;
                }
            }
            *(uint4*)&Bs[(it * 64 + srow) * LDK + skq] = v4;
        }
        __syncthreads();

        short8 af[SM], bf[SN];
        #pragma unroll
        for (int sm = 0; sm < SM; sm++)
            af[sm] = *(const short8*)&As[(wm + sm * 16 + (lane & 15)) * LDK + (lane >> 4) * 8];
        #pragma unroll
        for (int sn = 0; sn < SN; sn++)
            bf[sn] = *(const short8*)&Bs[(wn + sn * 16 + (lane & 15)) * LDK + (lane >> 4) * 8];
        #pragma unroll
        for (int sm = 0; sm < SM; sm++)
            #pragma unroll
            for (int sn = 0; sn < SN; sn++)
                acc[sm][sn] = __builtin_amdgcn_mfma_f32_16x16x32_bf16(af[sm], bf[sn], acc[sm][sn], 0, 0, 0);
        __syncthreads();
    }

    // epilogue: D mapping col=lane&15, row=(lane>>4)*4+r
    #pragma unroll
    for (int sm = 0; sm < SM; sm++) {
        #pragma unroll
        for (int sn = 0; sn < SN; sn++) {
            int n = n0 + wn + sn * 16 + (lane & 15);
            if (n >= N) continue;
            int mbase = m0 + wm + sm * 16 + ((lane >> 4) << 2);
            float vv[4];
            #pragma unroll
            for (int r = 0; r < 4; r++) {
                int m = mbase + r;
                float v = acc[sm][sn][r];
                if (do_relu) v = fmaxf(v, 0.f);
                if (bias) v += (bias_mode == 1) ? bias[m < M ? m : 0] : bias[n];
                if (bn_g) {
                    int node = n % NODEP; if (node > 134) node = 0;
                    long long gi = (long long)node * M + (m < M ? m : 0);
                    v = bn_g[gi] * (v * BN_SCALE) + bn_b[gi];
                }
                if (do_tanh) v = tanhf(v);
                long long addr = (long long)bz * sCbz + (long long)m * sCm + (long long)n * sCn;
                if (resid && m < M) v += resid[addr];
                vv[r] = v;
                if (m < M) {
                    if (C) C[addr] = v;
                    if (C16 && sCm != 1) C16[addr] = f2bf(v);
                }
            }
            if (C16 && sCm == 1 && mbase + 3 < M) {
                ushort4 pk;
                pk.x = f2bf(vv[0]); pk.y = f2bf(vv[1]); pk.z = f2bf(vv[2]); pk.w = f2bf(vv[3]);
                long long a0 = (long long)bz * sCbz + mbase + (long long)n * sCn;
                *(ushort4*)&C16[a0] = pk;
            }
        }
    }
}

// ---------------- attention scores + normalize ----------------
__global__ __launch_bounds__(256) void att_k(const float* __restrict__ kf, const float* __restrict__ qf,
                                             float* __restrict__ att) {
    int b = blockIdx.x;
    int tid = threadIdx.x;
    __shared__ float s[VN];
    __shared__ float red[4];
    __shared__ float ssum;
    float q0 = qf[b * DD + tid];
    float q1 = qf[b * DD + 256 + tid];
    const float* kb = kf + (long long)b * VN * DD;
    for (int v = 0; v < VN; v++) {
        float p = q0 * kb[v * DD + tid] + q1 * kb[v * DD + 256 + tid];
        for (int off = 32; off > 0; off >>= 1) p += __shfl_down(p, off);
        if ((tid & 63) == 0) red[tid >> 6] = p;
        __syncthreads();
        if (tid == 0) s[v] = red[0] + red[1] + red[2] + red[3] + 1e-15f;
        __syncthreads();
    }
    if (tid < 64) {
        float p2 = s[tid] + ((tid + 64) < VN ? s[tid + 64] : 0.f);
        for (int off = 32; off > 0; off >>= 1) p2 += __shfl_down(p2, off);
        if (tid == 0) ssum = p2;
    }
    __syncthreads();
    for (int v = tid; v < VN; v += 256) att[b * VN + v] = s[v] / ssum;
}

// ---------------- w34[b,t,f] = sum_v att[b,v] * poses[b,v+t,f] ----------------
__global__ void weighted_k(const float* __restrict__ poses, const float* __restrict__ att,
                           float* __restrict__ w34) {
    int t = blockIdx.x;
    int b = blockIdx.y;
    int f = threadIdx.x;
    if (f >= NF) return;
    const float* pb = poses + (long long)b * POSE_ROWS * NF + t * NF + f;
    const float* ab = att + b * VN;
    float acc = 0.f;
    for (int v = 0; v < VN; v++) acc += ab[v] * pb[v * NF];
    w34[(long long)b * DCTN * NF + t * NF + f] = acc;
}

// ---------------- x = concat(dct_in, dct_att); emit node-major f32 + feature-major bf16 ----
__global__ void build_x(const float* __restrict__ poses, const float* __restrict__ w34,
                        const float* __restrict__ dctm, float* __restrict__ x32,
                        ushort* __restrict__ xT16) {
    int idx = blockIdx.x * 256 + threadIdx.x;
    if (idx >= BATCH * NF * 68) return;
    int kk = idx % 68;
    int f = (idx / 68) % NF;
    int b = idx / (68 * NF);
    float acc = 0.f;
    if (kk < DCTN) {
        const float* pb = poses + (long long)b * POSE_ROWS * NF;
        #pragma unroll
        for (int t = 0; t < DCTN; t++) {
            int row = (t < KQ) ? (INN - KQ + t) : (INN - 1);
            acc += dctm[kk * DCTN + t] * pb[row * NF + f];
        }
    } else {
        int k2 = kk - DCTN;
        const float* wb = w34 + (long long)b * DCTN * NF + f;
        #pragma unroll
        for (int t = 0; t < DCTN; t++) acc += dctm[k2 * DCTN + t] * wb[t * NF];
    }
    long long R = (long long)b * NODEP + f;
    x32[R * 68 + kk] = acc;
    xT16[(long long)kk * RP + R] = f2bf(acc);
}

// ---------------- preds[b,t,f] = sum_k dct[k][10+t] * h32[b*136+f][k] ----------------
__global__ void idct_out(const float* __restrict__ h32, const float* __restrict__ dctm,
                         float* __restrict__ out) {
    int idx = blockIdx.x * 256 + threadIdx.x;
    if (idx >= BATCH * OUTN * NF) return;
    int f = idx % NF;
    int t = (idx / NF) % OUTN;
    int b = idx / (NF * OUTN);
    const float* yr = h32 + ((long long)b * NODEP + f) * 68;
    float acc = 0.f;
    #pragma unroll
    for (int k = 0; k < DCTN; k++) acc += dctm[k * DCTN + (KQ + t)] * yr[k];
    out[idx] = acc;
}

// ---------------- host ----------------
extern "C" void kernel_launch(void* const* d_in, const int* in_sizes, int n_in,
                              void* d_out, int out_size, void* d_ws, size_t ws_size,
                              hipStream_t stream) {
    const float* poses   = (const float*)d_in[0];
    const float* qw1     = (const float*)d_in[1];
    const float* qw2     = (const float*)d_in[2];
    const float* kw1     = (const float*)d_in[3];
    const float* kw2     = (const float*)d_in[4];
    const float* gc1_att = (const float*)d_in[5];
    const float* gc1_w   = (const float*)d_in[6];
    const float* gc1_b   = (const float*)d_in[7];
    const float* bn1_g   = (const float*)d_in[8];
    const float* bn1_b   = (const float*)d_in[9];
    const float* gcb_att = (const float*)d_in[10];
    const float* gcb_w   = (const float*)d_in[11];
    const float* gcb_b   = (const float*)d_in[12];
    const float* gcb_g   = (const float*)d_in[13];
    const float* gcb_beta= (const float*)d_in[14];
    const float* gc7_att = (const float*)d_in[15];
    const float* gc7_w   = (const float*)d_in[16];
    const float* gc7_b   = (const float*)d_in[17];
    float* out = (float*)d_out;
    float* w = (float*)d_ws;

    // ---- workspace layout (f32 units) ----
    float* dct  = w;                       // 1280
    float* att  = w + 1280;                // -> 23808
    float* w34  = w + 23808;               // -> 1198848
    float* x32  = w + 1198848;             // RP*68 -> 3566336
    float* h32  = w + 3566336;             // RP*68 -> 5933824
    float* qf   = w + 5933824;             // -> 6064896
    ushort* smallw = (ushort*)(w + 6064896);   // ~0.62M f32 -> 6684896
    ushort* WT1   = smallw;                    // 512*80
    ushort* WTb   = smallw + 40960;            // 4*512*512
    ushort* WT7   = smallw + 1089536;          // 68*512
    ushort* A16_1 = smallw + 1124352;          // 135*136
    ushort* A16_B = smallw + 1142712;          // 540*136
    ushort* A16_7 = smallw + 1216152;          // 135*136
    float*  R1 = w + 6684896;              // 17825792 f32
    float*  yT32 = R1;
    float*  kf   = R1;                     // phase-A alias (dead before yT32 written)
    ushort* R2 = (ushort*)(w + 24510688);  // 17825792 u16
    ushort* yT16 = R2;
    ushort* r1k16 = R2;                    // alias
    ushort* r1q16 = R2 + 11927552;
    ushort* R3 = (ushort*)(w + 33423584);
    ushort* hT16 = R3;
    ushort* pb16 = R3;                     // alias
    ushort* Wt1k = R3 + 5013504;
    ushort* Wt1q = R3 + 5431296;
    ushort* Wt2k = R3 + 5849088;
    ushort* Wt2q = R3 + 7159808;
    ushort* R4 = (ushort*)(w + 42336480);
    ushort* zN16 = R4;
    ushort* xT16 = R4;                     // alias
    ushort* z116 = R4 + 2367488;           // RP*80

    const long long INF_RPB = 1 << 30;

    // ---- prep ----
    dct_gen<<<19, 64, 0, stream>>>(dct);
    cvt_poses<<<(BATCH * POSE_ROWS * NODEP + 255) / 256, 256, 0, stream>>>(poses, pb16);
    pack_conv<<<(512*816 + 255)/256, 256, 0, stream>>>(kw1, Wt1k, 135, 6, 136, 816, 512*816);
    pack_conv<<<(512*816 + 255)/256, 256, 0, stream>>>(qw1, Wt1q, 135, 6, 136, 816, 512*816);
    pack_conv<<<(512*2560 + 255)/256, 256, 0, stream>>>(kw2, Wt2k, 512, 5, 512, 2560, 512*2560);
    pack_conv<<<(512*2560 + 255)/256, 256, 0, stream>>>(qw2, Wt2q, 512, 5, 512, 2560, 512*2560);
    transpose_cvt<<<(512*80 + 255)/256, 256, 0, stream>>>(gc1_w, WT1, 68, 512, 80, 512*80);
    for (int L = 0; L < 4; L++)
        transpose_cvt<<<(512*512 + 255)/256, 256, 0, stream>>>(gcb_w + L*262144, WTb + L*262144, 512, 512, 512, 512*512);
    transpose_cvt<<<(68*512 + 255)/256, 256, 0, stream>>>(gc7_w, WT7, 512, 68, 512, 68*512);
    cvt_pad_rows<<<(135*136 + 255)/256, 256, 0, stream>>>(gc1_att, A16_1, 135, 135, 136, 135*136);
    cvt_pad_rows<<<(540*136 + 255)/256, 256, 0, stream>>>(gcb_att, A16_B, 540, 135, 136, 540*136);
    cvt_pad_rows<<<(135*136 + 255)/256, 256, 0, stream>>>(gc7_att, A16_7, 135, 135, 136, 135*136);

    #define BIG(M_, N_, K_, A_, rpb_, sAw_, sAr_, sAbz_, Bt_, sBr_, C_, C16_, sCbz_, sCm_, sCn_, relu_, bias_, bmode_, bng_, bnb_, tanh_, resid_, bzn_) \
        gemm_mfma<128,128><<<dim3(((N_)+127)/128, ((M_)+127)/128, (bzn_)), 256, 0, stream>>>( \
            A_, Bt_, M_, N_, K_, rpb_, sAw_, sAr_, sAbz_, sBr_, C_, C16_, sCbz_, sCm_, sCn_, relu_, bias_, bmode_, bng_, bnb_, tanh_, resid_)
    #define SMALL(M_, N_, K_, A_, rpb_, sAw_, sAr_, sAbz_, Bt_, sBr_, C_, C16_, sCbz_, sCm_, sCn_, relu_, bias_, bmode_, bng_, bnb_, tanh_, resid_, bzn_) \
        gemm_mfma<64,64><<<dim3(((N_)+63)/64, ((M_)+63)/64, (bzn_)), 256, 0, stream>>>( \
            A_, Bt_, M_, N_, K_, rpb_, sAw_, sAr_, sAbz_, sBr_, C_, C16_, sCbz_, sCm_, sCn_, relu_, bias_, bmode_, bng_, bnb_, tanh_, resid_)

    // ---- conv stack (bf16 MFMA) ----
    BIG(23296, 512, 816, pb16, 91, 19584LL, 136LL, 0LL, Wt1k, 816LL,
        (float*)nullptr, r1k16, 0LL, 512LL, 1LL, 1, nullptr, 0, nullptr, nullptr, 0, nullptr, 1);
    BIG(1280, 512, 816, pb16 + 110*136, 5, 19584LL, 136LL, 0LL, Wt1q, 816LL,
        (float*)nullptr, r1q16, 0LL, 512LL, 1LL, 1, nullptr, 0, nullptr, nullptr, 0, nullptr, 1);
    BIG(22272, 512, 2560, r1k16, 87, 46592LL, 512LL, 0LL, Wt2k, 2560LL,
        kf, (ushort*)nullptr, 0LL, 512LL, 1LL, 1, nullptr, 0, nullptr, nullptr, 0, nullptr, 1);
    SMALL(256, 512, 2560, r1q16, (int)INF_RPB, 0LL, 2560LL, 0LL, Wt2q, 2560LL,
        qf, (ushort*)nullptr, 0LL, 512LL, 1LL, 1, nullptr, 0, nullptr, nullptr, 0, nullptr, 1);

    // ---- attention + x ----
    att_k<<<BATCH, 256, 0, stream>>>(kf, qf, att);
    weighted_k<<<dim3(DCTN, BATCH), 192, 0, stream>>>(poses, att, w34);
    build_x<<<(BATCH * NF * 68 + 255) / 256, 256, 0, stream>>>(poses, w34, dct, x32, xT16);

    // ---- gc1: mix (att@x) then W (68->512) ----
    SMALL(68, 135, 135, xT16, (int)INF_RPB, 0LL, (long long)RP, 136LL, A16_1, 136LL,
        (float*)nullptr, z116, 136LL*80, 1LL, 80LL, 0, nullptr, 0, nullptr, nullptr, 0, nullptr, BATCH);
    BIG(512, RP, 68, WT1, (int)INF_RPB, 0LL, 80LL, 0LL, z116, 80LL,
        yT32, yT16, 0LL, (long long)RP, 1LL, 0, gc1_b, 1, bn1_g, bn1_b, 1, nullptr, 1);

    // ---- residual GCN blocks ----
    for (int L = 0; L < 4; L++) {
        const ushort* min = (L & 1) ? hT16 : yT16;
        SMALL(512, 135, 135, min, (int)INF_RPB, 0LL, (long long)RP, 136LL, A16_B + L*18360, 136LL,
            (float*)nullptr, zN16, 136LL*512, 1LL, 512LL, 0, nullptr, 0, nullptr, nullptr, 0, nullptr, BATCH);
        if (!(L & 1)) {
            BIG(512, RP, 512, WTb + L*262144, (int)INF_RPB, 0LL, 512LL, 0LL, zN16, 512LL,
                (float*)nullptr, hT16, 0LL, (long long)RP, 1LL, 0, gcb_b + L*512, 1,
                gcb_g + L*69120, gcb_beta + L*69120, 1, nullptr, 1);
        } else {
            float* cf = (L == 1) ? yT32 : nullptr;   // block2 output only needed as bf16
            BIG(512, RP, 512, WTb + L*262144, (int)INF_RPB, 0LL, 512LL, 0LL, zN16, 512LL,
                cf, yT16, 0LL, (long long)RP, 1LL, 0, gcb_b + L*512, 1,
                gcb_g + L*69120, gcb_beta + L*69120, 1, yT32, 1);
        }
    }

    // ---- gc7: mix (att7@y) then W (512->68) + bias + x residual ----
    SMALL(512, 135, 135, yT16, (int)INF_RPB, 0LL, (long long)RP, 136LL, A16_7, 136LL,
        (float*)nullptr, zN16, 136LL*512, 1LL, 512LL, 0, nullptr, 0, nullptr, nullptr, 0, nullptr, BATCH);
    SMALL(RP, 68, 512, zN16, (int)INF_RPB, 0LL, 512LL, 0LL, WT7, 512LL,
        h32, (ushort*)nullptr, 0LL, 68LL, 1LL, 0, gc7_b, 2, nullptr, nullptr, 0, x32, 1);

    idct_out<<<(BATCH * OUTN * NF + 255) / 256, 256, 0, stream>>>(h32, dct, out);

    #undef BIG
    #undef SMALL
}

// Round 3
// 1180.428 us; speedup vs baseline: 3.4754x; 1.3841x over previous
//
#include <hip/hip_runtime.h>
#include <math.h>

// ---------------- problem constants ----------------
#define POSE_ROWS 144
#define NF 135
#define DD 512
#define KQ 10
#define DCTN 34
#define INN 120
#define OUTN 24
#define VN 87
#define BATCH 256
#define RP 34816              // padded row dim: 256 * 136
#define NODEP 136
#define BN_SCALE 0.9999950000374997f

typedef __attribute__((ext_vector_type(8))) short short8;
typedef __attribute__((ext_vector_type(4))) float floatx4;

static __device__ __forceinline__ ushort f2bf(float f) {
    unsigned u = __builtin_bit_cast(unsigned, f);
    u = (u + 0x7FFFu + ((u >> 16) & 1u)) >> 16;
    return (ushort)u;
}
static __device__ __forceinline__ float bf2f(ushort s) {
    return __builtin_bit_cast(float, (unsigned)s << 16);
}

#define GLOAD_LDS(gp, lp) __builtin_amdgcn_global_load_lds( \
    (const __attribute__((address_space(1))) unsigned int*)(const void*)(gp), \
    (__attribute__((address_space(3))) unsigned int*)(void*)(lp), 16, 0, 0)

// ---------------- small prep kernels ----------------
__global__ void zero_k(float* __restrict__ p) { p[threadIdx.x] = 0.f; }

__global__ void dct_gen(float* __restrict__ dct) {
    int idx = blockIdx.x * 64 + threadIdx.x;
    if (idx >= DCTN * DCTN) return;
    int k = idx / DCTN, i = idx % DCTN;
    double w = (k == 0) ? sqrt(1.0 / DCTN) : sqrt(2.0 / DCTN);
    dct[idx] = (float)(w * cos(3.14159265358979323846 * (i + 0.5) * k / (double)DCTN));
}

__global__ void cvt_poses(const float* __restrict__ poses, ushort* __restrict__ pb) {
    int idx = blockIdx.x * 256 + threadIdx.x;
    if (idx >= BATCH * POSE_ROWS * NODEP) return;
    int i = idx % NODEP;
    int row = (idx / NODEP) % POSE_ROWS;
    int b = idx / (NODEP * POSE_ROWS);
    float v = (i < NF) ? poses[((long long)b * POSE_ROWS + row) * NF + i] * 1e-3f : 0.f;
    pb[idx] = f2bf(v);
}

// conv weights: w[O][I][H] -> wt[o][k=h*padI+i] bf16, k padded to KP (zeros)
__global__ void pack_conv(const float* __restrict__ w, ushort* __restrict__ wt,
                          int I, int H, int padI, int KP, int total) {
    int idx = blockIdx.x * 256 + threadIdx.x;
    if (idx >= total) return;
    int n = idx / KP, k = idx % KP;
    int h = k / padI, i = k % padI;
    float v = (i < I && h < H) ? w[((long long)n * I + i) * H + h] : 0.f;
    wt[idx] = f2bf(v);
}

// W[k][n] f32 -> Wt[n][k] bf16, k padded to KP (zeros)
__global__ void transpose_cvt(const float* __restrict__ w, ushort* __restrict__ wt,
                              int Kd, int Nd, int KP, int total) {
    int idx = blockIdx.x * 256 + threadIdx.x;
    if (idx >= total) return;
    int n = idx / KP, k = idx % KP;
    float v = (k < Kd) ? w[(long long)k * Nd + n] : 0.f;
    wt[idx] = f2bf(v);
}

// att f32 [rows][cols] -> bf16 [rows][colsP] zero-padded
__global__ void cvt_pad_rows(const float* __restrict__ a, ushort* __restrict__ o,
                             int rows, int cols, int colsP, int total) {
    int idx = blockIdx.x * 256 + threadIdx.x;
    if (idx >= total) return;
    int r = idx / colsP, c = idx % colsP;
    o[idx] = f2bf(c < cols ? a[(long long)r * cols + c] : 0.f);
}

// bn params [node*512+m] -> [m*136+node] (coalesced for the W-GEMM epilogue)
__global__ void bn_t(const float* __restrict__ g, const float* __restrict__ b,
                     float* __restrict__ gt, float* __restrict__ bt) {
    int idx = blockIdx.x * 256 + threadIdx.x;
    if (idx >= 512 * 136) return;
    int node = idx % 136, m = idx / 136;
    gt[idx] = (node < 135) ? g[node * 512 + m] : 0.f;
    bt[idx] = (node < 135) ? b[node * 512 + m] : 0.f;
}

// ---------------- NT MFMA GEMM, BK=64, global_load_lds staging, XOR-swizzled LDS ----------
// C[m,n] = epi( sum_k A[m,k] * Bt[n,k] ) ; K must be a multiple of 64 and the
// zero-padded operand guarantees products vanish in the pad region.
// A row off = (m/rpbA)*sAw + (m%rpbA)*sAr + bz*sAbz ; Bt row off = n*sBr + bz*sBbz
// C addr = bz*sCbz + m*sCm + n*sCn (same map for C16/resid)
template<int BM, int BN>
__global__ __launch_bounds__(256) void gemm2(
    const ushort* __restrict__ A, const ushort* __restrict__ Bt,
    const ushort* __restrict__ zpad,
    int M, int N, int K,
    int rpbA, long long sAw, long long sAr, long long sAbz,
    long long sBr, long long sBbz,
    float* __restrict__ C, ushort* __restrict__ C16,
    long long sCbz, long long sCm, long long sCn,
    int do_relu, const float* __restrict__ bias, int bias_mode,
    const float* __restrict__ bnTg, const float* __restrict__ bnTb,
    int do_tanh, const ushort* __restrict__ resid16, const float* __restrict__ resid32)
{
    constexpr int SM = BM / 32, SN = BN / 32;
    constexpr int RA = BM / 32, RB = BN / 32;     // staging rounds, 32 rows each
    __shared__ ushort As[BM * 64];
    __shared__ ushort Bs[BN * 64];

    const int tid = threadIdx.x;
    const int lane = tid & 63, w = tid >> 6;
    const int bz = blockIdx.z;
    const int m0 = blockIdx.y * BM, n0 = blockIdx.x * BN;
    const int wm = (w >> 1) * (BM / 2), wn = (w & 1) * (BN / 2);
    // source chunk for this lane (XOR swizzle so ds_read_b128 is conflict-free)
    const int chunk = (lane & 7) ^ ((lane >> 3) & 7);

    const ushort* pA[RA]; int stA[RA];
    #pragma unroll
    for (int j = 0; j < RA; j++) {
        int m = m0 + j * 32 + w * 8 + (lane >> 3);
        bool v = m < M;
        long long off = v ? ((long long)(m / rpbA) * sAw + (long long)(m % rpbA) * sAr
                            + (long long)bz * sAbz) : 0;
        pA[j] = v ? (A + off + chunk * 8) : (zpad + chunk * 8);
        stA[j] = v ? 64 : 0;
    }
    const ushort* pB[RB]; int stB[RB];
    #pragma unroll
    for (int j = 0; j < RB; j++) {
        int n = n0 + j * 32 + w * 8 + (lane >> 3);
        bool v = n < N;
        long long off = v ? ((long long)n * sBr + (long long)bz * sBbz) : 0;
        pB[j] = v ? (Bt + off + chunk * 8) : (zpad + chunk * 8);
        stB[j] = v ? 64 : 0;
    }

    floatx4 acc[SM][SN];
    #pragma unroll
    for (int i = 0; i < SM; i++)
        #pragma unroll
        for (int j = 0; j < SN; j++)
            acc[i][j] = (floatx4){0.f, 0.f, 0.f, 0.f};

    for (int k0 = 0; k0 < K; k0 += 64) {
        #pragma unroll
        for (int j = 0; j < RA; j++)
            GLOAD_LDS(pA[j], &As[(j * 32 + w * 8) * 64]);
        #pragma unroll
        for (int j = 0; j < RB; j++)
            GLOAD_LDS(pB[j], &Bs[(j * 32 + w * 8) * 64]);
        __syncthreads();

        #pragma unroll
        for (int kk = 0; kk < 2; kk++) {
            short8 af[SM], bf[SN];
            #pragma unroll
            for (int sm = 0; sm < SM; sm++) {
                int lr = wm + sm * 16 + (lane & 15);
                int slot = ((lane >> 4) + kk * 4) ^ (lr & 7);
                af[sm] = *(const short8*)&As[lr * 64 + slot * 8];
            }
            #pragma unroll
            for (int sn = 0; sn < SN; sn++) {
                int lr = wn + sn * 16 + (lane & 15);
                int slot = ((lane >> 4) + kk * 4) ^ (lr & 7);
                bf[sn] = *(const short8*)&Bs[lr * 64 + slot * 8];
            }
            #pragma unroll
            for (int sm = 0; sm < SM; sm++)
                #pragma unroll
                for (int sn = 0; sn < SN; sn++)
                    acc[sm][sn] = __builtin_amdgcn_mfma_f32_16x16x32_bf16(af[sm], bf[sn], acc[sm][sn], 0, 0, 0);
        }
        __syncthreads();

        #pragma unroll
        for (int j = 0; j < RA; j++) pA[j] += stA[j];
        #pragma unroll
        for (int j = 0; j < RB; j++) pB[j] += stB[j];
    }

    // epilogue: D mapping col(n)=lane&15, row(m)=(lane>>4)*4+r
    const int lc = lane & 15;
    const int lr4 = (lane >> 4) << 2;
    #pragma unroll
    for (int sm = 0; sm < SM; sm++) {
        #pragma unroll
        for (int sn = 0; sn < SN; sn++) {
            int n = n0 + wn + sn * 16 + lc;
            if (n >= N) continue;
            int node = n % 136;
            int mb = m0 + wm + sm * 16 + lr4;
            float vv[4];
            #pragma unroll
            for (int r = 0; r < 4; r++) {
                int m = mb + r;
                float v = acc[sm][sn][r];
                if (do_relu) v = fmaxf(v, 0.f);
                if (bias) v += (bias_mode == 1) ? bias[m < M ? m : 0] : bias[n];
                if (bnTg) {
                    long long gi = (long long)(m < M ? m : 0) * 136 + node;
                    v = bnTg[gi] * (v * BN_SCALE) + bnTb[gi];
                }
                if (do_tanh) v = tanhf(v);
                long long addr = (long long)bz * sCbz + (long long)m * sCm + (long long)n * sCn;
                if (m < M) {
                    if (resid16) v += bf2f(resid16[addr]);
                    else if (resid32) v += resid32[addr];
                    if (C) C[addr] = v;
                    if (C16 && sCm != 1) C16[addr] = f2bf(v);
                }
                vv[r] = v;
            }
            if (C16 && sCm == 1 && mb + 3 < M) {
                ushort4 pk;
                pk.x = f2bf(vv[0]); pk.y = f2bf(vv[1]); pk.z = f2bf(vv[2]); pk.w = f2bf(vv[3]);
                *(ushort4*)&C16[(long long)bz * sCbz + mb + (long long)n * sCn] = pk;
            }
        }
    }
}

// ---------------- attention scores + normalize ----------------
__global__ __launch_bounds__(256) void att_k(const float* __restrict__ kf, const float* __restrict__ qf,
                                             float* __restrict__ att) {
    int b = blockIdx.x;
    int tid = threadIdx.x;
    __shared__ float s[VN];
    __shared__ float red[4];
    __shared__ float ssum;
    float q0 = qf[b * DD + tid];
    float q1 = qf[b * DD + 256 + tid];
    const float* kb = kf + (long long)b * VN * DD;
    for (int v = 0; v < VN; v++) {
        float p = q0 * kb[v * DD + tid] + q1 * kb[v * DD + 256 + tid];
        for (int off = 32; off > 0; off >>= 1) p += __shfl_down(p, off);
        if ((tid & 63) == 0) red[tid >> 6] = p;
        __syncthreads();
        if (tid == 0) s[v] = red[0] + red[1] + red[2] + red[3] + 1e-15f;
        __syncthreads();
    }
    if (tid < 64) {
        float p2 = s[tid] + ((tid + 64) < VN ? s[tid + 64] : 0.f);
        for (int off = 32; off > 0; off >>= 1) p2 += __shfl_down(p2, off);
        if (tid == 0) ssum = p2;
    }
    __syncthreads();
    for (int v = tid; v < VN; v += 256) att[b * VN + v] = s[v] / ssum;
}

// ---------------- w34[b,t,f] = sum_v att[b,v] * poses[b,v+t,f] ----------------
__global__ void weighted_k(const float* __restrict__ poses, const float* __restrict__ att,
                           float* __restrict__ w34) {
    int t = blockIdx.x;
    int b = blockIdx.y;
    int f = threadIdx.x;
    if (f >= NF) return;
    const float* pb = poses + (long long)b * POSE_ROWS * NF + t * NF + f;
    const float* ab = att + b * VN;
    float acc = 0.f;
    for (int v = 0; v < VN; v++) acc += ab[v] * pb[v * NF];
    w34[(long long)b * DCTN * NF + t * NF + f] = acc;
}

// ---------------- x = concat(dct_in, dct_att); node-major f32 + feature-major bf16 ----
__global__ void build_x(const float* __restrict__ poses, const float* __restrict__ w34,
                        const float* __restrict__ dctm, float* __restrict__ x32,
                        ushort* __restrict__ xT16) {
    int idx = blockIdx.x * 256 + threadIdx.x;
    if (idx >= BATCH * NF * 68) return;
    int kk = idx % 68;
    int f = (idx / 68) % NF;
    int b = idx / (68 * NF);
    float acc = 0.f;
    if (kk < DCTN) {
        const float* pb = poses + (long long)b * POSE_ROWS * NF;
        #pragma unroll
        for (int t = 0; t < DCTN; t++) {
            int row = (t < KQ) ? (INN - KQ + t) : (INN - 1);
            acc += dctm[kk * DCTN + t] * pb[row * NF + f];
        }
    } else {
        int k2 = kk - DCTN;
        const float* wb = w34 + (long long)b * DCTN * NF + f;
        #pragma unroll
        for (int t = 0; t < DCTN; t++) acc += dctm[k2 * DCTN + t] * wb[t * NF];
    }
    long long R = (long long)b * NODEP + f;
    x32[R * 68 + kk] = acc;
    xT16[(long long)kk * RP + R] = f2bf(acc);
}

// ---------------- preds[b,t,f] = sum_k dct[k][10+t] * h32[(b*136+f)*68+k] ----------------
__global__ void idct_out(const float* __restrict__ h32, const float* __restrict__ dctm,
                         float* __restrict__ out) {
    int idx = blockIdx.x * 256 + threadIdx.x;
    if (idx >= BATCH * OUTN * NF) return;
    int f = idx % NF;
    int t = (idx / NF) % OUTN;
    int b = idx / (NF * OUTN);
    const float* yr = h32 + ((long long)b * NODEP + f) * 68;
    float acc = 0.f;
    #pragma unroll
    for (int k = 0; k < DCTN; k++) acc += dctm[k * DCTN + (KQ + t)] * yr[k];
    out[idx] = acc;
}

// ---------------- host ----------------
extern "C" void kernel_launch(void* const* d_in, const int* in_sizes, int n_in,
                              void* d_out, int out_size, void* d_ws, size_t ws_size,
                              hipStream_t stream) {
    const float* poses   = (const float*)d_in[0];
    const float* qw1     = (const float*)d_in[1];
    const float* qw2     = (const float*)d_in[2];
    const float* kw1     = (const float*)d_in[3];
    const float* kw2     = (const float*)d_in[4];
    const float* gc1_att = (const float*)d_in[5];
    const float* gc1_w   = (const float*)d_in[6];
    const float* gc1_b   = (const float*)d_in[7];
    const float* bn1_g   = (const float*)d_in[8];
    const float* bn1_b   = (const float*)d_in[9];
    const float* gcb_att = (const float*)d_in[10];
    const float* gcb_w   = (const float*)d_in[11];
    const float* gcb_b   = (const float*)d_in[12];
    const float* gcb_g   = (const float*)d_in[13];
    const float* gcb_beta= (const float*)d_in[14];
    const float* gc7_att = (const float*)d_in[15];
    const float* gc7_w   = (const float*)d_in[16];
    const float* gc7_b   = (const float*)d_in[17];
    float* out = (float*)d_out;
    float* w = (float*)d_ws;

    // ---- workspace layout (f32 units) ----
    float* dct   = w;                      // 1156 -> pad 1280
    float* att   = w + 1280;               // 22272 -> 23808
    float* w34   = w + 23808;              // 1175040 -> 1198848
    float* x32   = w + 1198848;            // RP*68 -> 3566336
    float* h32   = w + 3566336;            // RP*68 -> 5933824
    float* qf    = w + 5933824;            // 131072 -> 6064896
    ushort* su   = (ushort*)(w + 6064896); // bf16 weight region
    ushort* WT1    = su;                   // 512*128   = 65536
    ushort* WTb    = su + 65536;           // 4*512*512 = 1048576
    ushort* WT7    = su + 1114112;         // 68*512    = 34816
    ushort* A16_1  = su + 1148928;         // 135*192   = 25920
    ushort* A16_B  = su + 1174848;         // 540*192   = 103680
    ushort* A16_7  = su + 1278528;         // 25920 -> su ends 1304448u = 652224 f
    float* bnT   = w + 6717120;            // 10 * 69632 -> 7413440
    float* kf    = w + 7413440;            // 256*87*512 = 11403264 -> 18816704
    ushort* R2   = (ushort*)(w + 18816704);// 17825792 u
    ushort* yT16  = R2;
    ushort* r1k16 = R2;                    // phase-A alias
    ushort* r1q16 = R2 + 11927552;
    ushort* R3   = (ushort*)(w + 27729600);// 17825792 u
    ushort* hT16  = R3;
    ushort* pb16  = R3;                    // phase-A alias
    ushort* Wt1k  = R3 + 5013504;
    ushort* Wt1q  = R3 + 5439488;
    ushort* Wt2k  = R3 + 5865472;
    ushort* Wt2q  = R3 + 7176192;
    ushort* R4   = (ushort*)(w + 36642496);// 17825792 u
    ushort* zN16  = R4;
    ushort* xT16  = R4;                    // alias (dead before zN16 written)
    ushort* z116  = R4 + 2367488;          // RP*80
    float* zpadf = w + 45555392;           // 128 f zero page
    const ushort* zpad = (const ushort*)zpadf;

    const int INF_RPB = 1 << 30;

    // ---- prep ----
    zero_k<<<1, 128, 0, stream>>>(zpadf);
    dct_gen<<<19, 64, 0, stream>>>(dct);
    cvt_poses<<<(BATCH * POSE_ROWS * NODEP + 255) / 256, 256, 0, stream>>>(poses, pb16);
    pack_conv<<<(512*832 + 255)/256, 256, 0, stream>>>(kw1, Wt1k, 135, 6, 136, 832, 512*832);
    pack_conv<<<(512*832 + 255)/256, 256, 0, stream>>>(qw1, Wt1q, 135, 6, 136, 832, 512*832);
    pack_conv<<<(512*2560 + 255)/256, 256, 0, stream>>>(kw2, Wt2k, 512, 5, 512, 2560, 512*2560);
    pack_conv<<<(512*2560 + 255)/256, 256, 0, stream>>>(qw2, Wt2q, 512, 5, 512, 2560, 512*2560);
    transpose_cvt<<<(512*128 + 255)/256, 256, 0, stream>>>(gc1_w, WT1, 68, 512, 128, 512*128);
    for (int L = 0; L < 4; L++)
        transpose_cvt<<<(512*512 + 255)/256, 256, 0, stream>>>(gcb_w + L*262144, WTb + L*262144, 512, 512, 512, 512*512);
    transpose_cvt<<<(68*512 + 255)/256, 256, 0, stream>>>(gc7_w, WT7, 512, 68, 512, 68*512);
    cvt_pad_rows<<<(135*192 + 255)/256, 256, 0, stream>>>(gc1_att, A16_1, 135, 135, 192, 135*192);
    cvt_pad_rows<<<(540*192 + 255)/256, 256, 0, stream>>>(gcb_att, A16_B, 540, 135, 192, 540*192);
    cvt_pad_rows<<<(135*192 + 255)/256, 256, 0, stream>>>(gc7_att, A16_7, 135, 135, 192, 135*192);
    bn_t<<<(512*136 + 255)/256, 256, 0, stream>>>(bn1_g, bn1_b, bnT, bnT + 69632);
    for (int L = 0; L < 4; L++)
        bn_t<<<(512*136 + 255)/256, 256, 0, stream>>>(gcb_g + L*69120, gcb_beta + L*69120,
                                                      bnT + (1 + L) * 139264, bnT + (1 + L) * 139264 + 69632);

    // ---- conv stack ----
    gemm2<128,128><<<dim3(4, 182, 1), 256, 0, stream>>>(pb16, Wt1k, zpad, 23296, 512, 832,
        91, 19584LL, 136LL, 0LL, 832LL, 0LL,
        (float*)nullptr, r1k16, 0LL, 512LL, 1LL, 1, nullptr, 0, nullptr, nullptr, 0, nullptr, nullptr);
    gemm2<128,128><<<dim3(4, 10, 1), 256, 0, stream>>>(pb16 + 110*136, Wt1q, zpad, 1280, 512, 832,
        5, 19584LL, 136LL, 0LL, 832LL, 0LL,
        (float*)nullptr, r1q16, 0LL, 512LL, 1LL, 1, nullptr, 0, nullptr, nullptr, 0, nullptr, nullptr);
    gemm2<128,128><<<dim3(4, 174, 1), 256, 0, stream>>>(r1k16, Wt2k, zpad, 22272, 512, 2560,
        87, 46592LL, 512LL, 0LL, 2560LL, 0LL,
        kf, (ushort*)nullptr, 0LL, 512LL, 1LL, 1, nullptr, 0, nullptr, nullptr, 0, nullptr, nullptr);
    gemm2<64,64><<<dim3(8, 4, 1), 256, 0, stream>>>(r1q16, Wt2q, zpad, 256, 512, 2560,
        INF_RPB, 0LL, 2560LL, 0LL, 2560LL, 0LL,
        qf, (ushort*)nullptr, 0LL, 512LL, 1LL, 1, nullptr, 0, nullptr, nullptr, 0, nullptr, nullptr);

    // ---- attention + x ----
    att_k<<<BATCH, 256, 0, stream>>>(kf, qf, att);
    weighted_k<<<dim3(DCTN, BATCH), 192, 0, stream>>>(poses, att, w34);
    build_x<<<(BATCH * NF * 68 + 255) / 256, 256, 0, stream>>>(poses, w34, dct, x32, xT16);

    // ---- gc1: mix then W(68->512) ----
    gemm2<64,64><<<dim3(3, 2, BATCH), 256, 0, stream>>>(xT16, A16_1, zpad, 68, 135, 192,
        INF_RPB, 0LL, (long long)RP, 136LL, 192LL, 0LL,
        (float*)nullptr, z116, 10880LL, 1LL, 80LL, 0, nullptr, 0, nullptr, nullptr, 0, nullptr, nullptr);
    gemm2<128,128><<<dim3(272, 4, 1), 256, 0, stream>>>(WT1, z116, zpad, 512, RP, 128,
        INF_RPB, 0LL, 128LL, 0LL, 80LL, 0LL,
        (float*)nullptr, yT16, 0LL, (long long)RP, 1LL, 0, gc1_b, 1, bnT, bnT + 69632, 1, nullptr, nullptr);

    // ---- residual GCN blocks ----
    for (int L = 0; L < 4; L++) {
        const ushort* min = (L & 1) ? hT16 : yT16;
        gemm2<64,64><<<dim3(3, 8, BATCH), 256, 0, stream>>>(min, A16_B + L*25920, zpad, 512, 135, 192,
            INF_RPB, 0LL, (long long)RP, 136LL, 192LL, 0LL,
            (float*)nullptr, zN16, 69632LL, 1LL, 512LL, 0, nullptr, 0, nullptr, nullptr, 0, nullptr, nullptr);
        gemm2<128,128><<<dim3(272, 4, 1), 256, 0, stream>>>(WTb + L*262144, zN16, zpad, 512, RP, 512,
            INF_RPB, 0LL, 512LL, 0LL, 512LL, 0LL,
            (float*)nullptr, (L & 1) ? yT16 : hT16, 0LL, (long long)RP, 1LL,
            0, gcb_b + L*512, 1, bnT + (1 + L) * 139264, bnT + (1 + L) * 139264 + 69632, 1,
            (L & 1) ? yT16 : (const ushort*)nullptr, nullptr);
    }

    // ---- gc7: mix then W(512->68) + bias + x residual ----
    gemm2<64,64><<<dim3(3, 8, BATCH), 256, 0, stream>>>(yT16, A16_7, zpad, 512, 135, 192,
        INF_RPB, 0LL, (long long)RP, 136LL, 192LL, 0LL,
        (float*)nullptr, zN16, 69632LL, 1LL, 512LL, 0, nullptr, 0, nullptr, nullptr, 0, nullptr, nullptr);
    gemm2<64,64><<<dim3(2, 544, 1), 256, 0, stream>>>(zN16, WT7, zpad, RP, 68, 512,
        INF_RPB, 0LL, 512LL, 0LL, 512LL, 0LL,
        h32, (ushort*)nullptr, 0LL, 68LL, 1LL, 0, gc7_b, 2, nullptr, nullptr, 0, nullptr, x32);

    idct_out<<<(BATCH * OUTN * NF + 255) / 256, 256, 0, stream>>>(h32, dct, out);
}

// Round 4
// 1087.789 us; speedup vs baseline: 3.7714x; 1.0852x over previous
//
#include <hip/hip_runtime.h>
#include <math.h>

// ---------------- problem constants ----------------
#define POSE_ROWS 144
#define NF 135
#define DD 512
#define KQ 10
#define DCTN 34
#define INN 120
#define OUTN 24
#define VN 87
#define BATCH 256
#define RP 34816              // padded row dim: 256 * 136
#define NODEP 136
#define BN_SCALE 0.9999950000374997f

typedef __attribute__((ext_vector_type(8))) short short8;
typedef __attribute__((ext_vector_type(4))) float floatx4;

static __device__ __forceinline__ ushort f2bf(float f) {
    unsigned u = __builtin_bit_cast(unsigned, f);
    u = (u + 0x7FFFu + ((u >> 16) & 1u)) >> 16;
    return (ushort)u;
}
static __device__ __forceinline__ float bf2f(ushort s) {
    return __builtin_bit_cast(float, (unsigned)s << 16);
}
// fast tanh: tanh(|x|) = (1-e^{-2|x|})/(1+e^{-2|x|}), ~6 VALU vs ~28 for tanhf
static __device__ __forceinline__ float tanh_fast(float x) {
    float ax = __builtin_fabsf(x);
    float e = __builtin_amdgcn_exp2f(ax * -2.885390081777927f);   // e^{-2ax}
    float t = (1.f - e) * __builtin_amdgcn_rcpf(1.f + e);
    return __builtin_copysignf(t, x);
}

#define GLOAD_LDS(gp, lp) __builtin_amdgcn_global_load_lds( \
    (const __attribute__((address_space(1))) unsigned int*)(const void*)(gp), \
    (__attribute__((address_space(3))) unsigned int*)(void*)(lp), 16, 0, 0)

// ---------------- fused prep kernel (all weight repacks / converts in ONE dispatch) ----
// segment boundaries in 256-thread blocks:
#define PB_POSES 19584
#define PB_K1A   21248
#define PB_K1B   22912
#define PB_K2A   28032
#define PB_K2B   33152
#define PB_WT1   33408
#define PB_WTB   37504
#define PB_WT7   37640
#define PB_A1    37742
#define PB_AB    38147
#define PB_A7    38249
#define PB_BN    39609
#define PB_Z     39610
#define PB_DCT   39615

__global__ __launch_bounds__(256) void prep_all(
    const float* __restrict__ poses, ushort* __restrict__ pb16,
    const float* __restrict__ kw1, const float* __restrict__ qw1,
    ushort* __restrict__ Wt1k, ushort* __restrict__ Wt1q,
    const float* __restrict__ kw2, const float* __restrict__ qw2,
    ushort* __restrict__ Wt2k, ushort* __restrict__ Wt2q,
    const float* __restrict__ gc1_w, ushort* __restrict__ WT1,
    const float* __restrict__ gcb_w, ushort* __restrict__ WTb,
    const float* __restrict__ gc7_w, ushort* __restrict__ WT7,
    const float* __restrict__ gc1_att, ushort* __restrict__ A16_1,
    const float* __restrict__ gcb_att, ushort* __restrict__ A16_B,
    const float* __restrict__ gc7_att, ushort* __restrict__ A16_7,
    const float* __restrict__ bn1_g, const float* __restrict__ bn1_b,
    const float* __restrict__ gcb_g, const float* __restrict__ gcb_beta,
    float* __restrict__ bnT, float* __restrict__ zpadf, float* __restrict__ dct)
{
    const int blk = blockIdx.x;
    const int tid = threadIdx.x;
    if (blk < PB_POSES) {
        int idx = blk * 256 + tid;
        int i = idx % NODEP;
        int row = (idx / NODEP) % POSE_ROWS;
        int b = idx / (NODEP * POSE_ROWS);
        float v = (i < NF) ? poses[((long long)b * POSE_ROWS + row) * NF + i] * 1e-3f : 0.f;
        pb16[idx] = f2bf(v);
    } else if (blk < PB_K1B) {
        int wi = blk - PB_POSES;
        const float* src = (wi < 1664) ? kw1 : qw1;
        ushort* dst = (wi < 1664) ? Wt1k : Wt1q;
        int idx = (wi % 1664) * 256 + tid;
        int n = idx / 832, k = idx % 832;
        int h = k / 136, i = k % 136;
        float v = (i < 135 && h < 6) ? src[((long long)n * 135 + i) * 6 + h] : 0.f;
        dst[idx] = f2bf(v);
    } else if (blk < PB_K2B) {
        int wi = blk - PB_K1B;
        const float* src = (wi < 5120) ? kw2 : qw2;
        ushort* dst = (wi < 5120) ? Wt2k : Wt2q;
        int idx = (wi % 5120) * 256 + tid;
        int n = idx / 2560, k = idx % 2560;
        int h = k / 512, i = k % 512;
        dst[idx] = f2bf(src[((long long)n * 512 + i) * 5 + h]);
    } else if (blk < PB_WT1) {
        int idx = (blk - PB_K2B) * 256 + tid;
        int n = idx / 128, k = idx % 128;
        WT1[idx] = f2bf((k < 68) ? gc1_w[(long long)k * 512 + n] : 0.f);
    } else if (blk < PB_WTB) {
        int g = (blk - PB_WT1) * 256 + tid;
        int L = g >> 18, idx = g & 262143;
        int n = idx / 512, k = idx % 512;
        WTb[g] = f2bf(gcb_w[(long long)L * 262144 + (long long)k * 512 + n]);
    } else if (blk < PB_WT7) {
        int idx = (blk - PB_WTB) * 256 + tid;
        int n = idx / 512, k = idx % 512;
        WT7[idx] = f2bf(gc7_w[(long long)k * 68 + n]);
    } else if (blk < PB_A1) {
        int idx = (blk - PB_WT7) * 256 + tid;
        if (idx < 135 * 192) {
            int r = idx / 192, c = idx % 192;
            A16_1[idx] = f2bf(c < 135 ? gc1_att[r * 135 + c] : 0.f);
        }
    } else if (blk < PB_AB) {
        int idx = (blk - PB_A1) * 256 + tid;
        int r = idx / 192, c = idx % 192;
        A16_B[idx] = f2bf(c < 135 ? gcb_att[r * 135 + c] : 0.f);
    } else if (blk < PB_A7) {
        int idx = (blk - PB_AB) * 256 + tid;
        if (idx < 135 * 192) {
            int r = idx / 192, c = idx % 192;
            A16_7[idx] = f2bf(c < 135 ? gc7_att[r * 135 + c] : 0.f);
        }
    } else if (blk < PB_BN) {
        int g = (blk - PB_A7) * 256 + tid;
        int p = g / 69632, idx = g % 69632;
        int node = idx % 136, m = idx / 136;
        const float* gs = (p == 0) ? bn1_g : (gcb_g + (p - 1) * 69120);
        const float* bs = (p == 0) ? bn1_b : (gcb_beta + (p - 1) * 69120);
        float* gt = bnT + (long long)p * 139264;
        float* bt = gt + 69632;
        gt[idx] = (node < 135) ? gs[node * 512 + m] : 0.f;
        bt[idx] = (node < 135) ? bs[node * 512 + m] : 0.f;
    } else if (blk < PB_Z) {
        if (tid < 128) zpadf[tid] = 0.f;
    } else {
        int idx = (blk - PB_Z) * 256 + tid;
        if (idx < DCTN * DCTN) {
            int k = idx / DCTN, i = idx % DCTN;
            double w = (k == 0) ? sqrt(1.0 / DCTN) : sqrt(2.0 / DCTN);
            dct[idx] = (float)(w * cos(3.14159265358979323846 * (i + 0.5) * k / (double)DCTN));
        }
    }
}

// ---------------- NT MFMA GEMM, BK=64, global_load_lds staging, XOR-swizzled LDS ----------
template<int BM, int BN>
__global__ __launch_bounds__(256) void gemm2(
    const ushort* __restrict__ A, const ushort* __restrict__ Bt,
    const ushort* __restrict__ zpad,
    int M, int N, int K,
    int rpbA, long long sAw, long long sAr, long long sAbz,
    long long sBr, long long sBbz,
    float* __restrict__ C, ushort* __restrict__ C16,
    long long sCbz, long long sCm, long long sCn,
    int do_relu, const float* __restrict__ bias, int bias_mode,
    const float* __restrict__ bnTg, const float* __restrict__ bnTb,
    int do_tanh, const ushort* __restrict__ resid16, const float* __restrict__ resid32)
{
    constexpr int SM = BM / 32, SN = BN / 32;
    constexpr int RA = BM / 32, RB = BN / 32;     // staging rounds, 32 rows each
    __shared__ ushort As[BM * 64];
    __shared__ ushort Bs[BN * 64];

    const int tid = threadIdx.x;
    const int lane = tid & 63, w = tid >> 6;
    const int bz = blockIdx.z;
    const int m0 = blockIdx.y * BM, n0 = blockIdx.x * BN;
    const int wm = (w >> 1) * (BM / 2), wn = (w & 1) * (BN / 2);
    const int chunk = (lane & 7) ^ ((lane >> 3) & 7);

    const ushort* pA[RA]; int stA[RA];
    #pragma unroll
    for (int j = 0; j < RA; j++) {
        int m = m0 + j * 32 + w * 8 + (lane >> 3);
        bool v = m < M;
        long long off = v ? ((long long)(m / rpbA) * sAw + (long long)(m % rpbA) * sAr
                            + (long long)bz * sAbz) : 0;
        pA[j] = v ? (A + off + chunk * 8) : (zpad + chunk * 8);
        stA[j] = v ? 64 : 0;
    }
    const ushort* pB[RB]; int stB[RB];
    #pragma unroll
    for (int j = 0; j < RB; j++) {
        int n = n0 + j * 32 + w * 8 + (lane >> 3);
        bool v = n < N;
        long long off = v ? ((long long)n * sBr + (long long)bz * sBbz) : 0;
        pB[j] = v ? (Bt + off + chunk * 8) : (zpad + chunk * 8);
        stB[j] = v ? 64 : 0;
    }

    floatx4 acc[SM][SN];
    #pragma unroll
    for (int i = 0; i < SM; i++)
        #pragma unroll
        for (int j = 0; j < SN; j++)
            acc[i][j] = (floatx4){0.f, 0.f, 0.f, 0.f};

    for (int k0 = 0; k0 < K; k0 += 64) {
        #pragma unroll
        for (int j = 0; j < RA; j++)
            GLOAD_LDS(pA[j], &As[(j * 32 + w * 8) * 64]);
        #pragma unroll
        for (int j = 0; j < RB; j++)
            GLOAD_LDS(pB[j], &Bs[(j * 32 + w * 8) * 64]);
        __syncthreads();

        #pragma unroll
        for (int kk = 0; kk < 2; kk++) {
            short8 af[SM], bf[SN];
            #pragma unroll
            for (int sm = 0; sm < SM; sm++) {
                int lr = wm + sm * 16 + (lane & 15);
                int slot = ((lane >> 4) + kk * 4) ^ (lr & 7);
                af[sm] = *(const short8*)&As[lr * 64 + slot * 8];
            }
            #pragma unroll
            for (int sn = 0; sn < SN; sn++) {
                int lr = wn + sn * 16 + (lane & 15);
                int slot = ((lane >> 4) + kk * 4) ^ (lr & 7);
                bf[sn] = *(const short8*)&Bs[lr * 64 + slot * 8];
            }
            #pragma unroll
            for (int sm = 0; sm < SM; sm++)
                #pragma unroll
                for (int sn = 0; sn < SN; sn++)
                    acc[sm][sn] = __builtin_amdgcn_mfma_f32_16x16x32_bf16(af[sm], bf[sn], acc[sm][sn], 0, 0, 0);
        }
        __syncthreads();

        #pragma unroll
        for (int j = 0; j < RA; j++) pA[j] += stA[j];
        #pragma unroll
        for (int j = 0; j < RB; j++) pB[j] += stB[j];
    }

    // epilogue: D mapping col(n)=lane&15, row(m)=(lane>>4)*4+r
    const int lc = lane & 15;
    const int lr4 = (lane >> 4) << 2;
    #pragma unroll
    for (int sm = 0; sm < SM; sm++) {
        #pragma unroll
        for (int sn = 0; sn < SN; sn++) {
            int n = n0 + wn + sn * 16 + lc;
            if (n >= N) continue;
            int node = n % 136;
            int mb = m0 + wm + sm * 16 + lr4;
            float vv[4];
            #pragma unroll
            for (int r = 0; r < 4; r++) {
                int m = mb + r;
                float v = acc[sm][sn][r];
                if (do_relu) v = fmaxf(v, 0.f);
                if (bias) v += (bias_mode == 1) ? bias[m < M ? m : 0] : bias[n];
                if (bnTg) {
                    long long gi = (long long)(m < M ? m : 0) * 136 + node;
                    v = bnTg[gi] * (v * BN_SCALE) + bnTb[gi];
                }
                if (do_tanh) v = tanh_fast(v);
                long long addr = (long long)bz * sCbz + (long long)m * sCm + (long long)n * sCn;
                if (m < M) {
                    if (resid16) v += bf2f(resid16[addr]);
                    else if (resid32) v += resid32[addr];
                    if (C) C[addr] = v;
                    if (C16 && sCm != 1) C16[addr] = f2bf(v);
                }
                vv[r] = v;
            }
            if (C16 && sCm == 1 && mb + 3 < M) {
                ushort4 pk;
                pk.x = f2bf(vv[0]); pk.y = f2bf(vv[1]); pk.z = f2bf(vv[2]); pk.w = f2bf(vv[3]);
                *(ushort4*)&C16[(long long)bz * sCbz + mb + (long long)n * sCn] = pk;
            }
        }
    }
}

// ---------------- attention scores + normalize (wave-parallel) ----------------
__global__ __launch_bounds__(256) void att_k(const float* __restrict__ kf, const float* __restrict__ qf,
                                             float* __restrict__ att) {
    int b = blockIdx.x;
    int tid = threadIdx.x;
    int lane = tid & 63, w = tid >> 6;
    __shared__ float s[96];
    __shared__ float ssum;
    const float* qb = qf + b * DD + lane * 8;
    float4 q0 = *(const float4*)qb;
    float4 q1 = *(const float4*)(qb + 4);
    const float* kb = kf + (long long)b * VN * DD;
    for (int v = w; v < VN; v += 4) {
        const float* kr = kb + v * DD + lane * 8;
        float4 k0 = *(const float4*)kr;
        float4 k1 = *(const float4*)(kr + 4);
        float p = q0.x * k0.x + q0.y * k0.y + q0.z * k0.z + q0.w * k0.w
                + q1.x * k1.x + q1.y * k1.y + q1.z * k1.z + q1.w * k1.w;
        #pragma unroll
        for (int off = 32; off; off >>= 1) p += __shfl_xor(p, off);
        if (lane == 0) s[v] = p + 1e-15f;
    }
    __syncthreads();
    if (tid < 64) {
        float p2 = (tid < VN ? s[tid] : 0.f) + ((tid + 64) < VN ? s[tid + 64] : 0.f);
        #pragma unroll
        for (int off = 32; off; off >>= 1) p2 += __shfl_xor(p2, off);
        if (tid == 0) ssum = p2;
    }
    __syncthreads();
    float inv = 1.f / ssum;
    for (int v = tid; v < VN; v += 256) att[b * VN + v] = s[v] * inv;
}

// ---------------- w34[b,t,f] = sum_v att[b,v] * poses[b,v+t,f] ----------------
__global__ void weighted_k(const float* __restrict__ poses, const float* __restrict__ att,
                           float* __restrict__ w34) {
    int t = blockIdx.x;
    int b = blockIdx.y;
    int f = threadIdx.x;
    if (f >= NF) return;
    const float* pb = poses + (long long)b * POSE_ROWS * NF + t * NF + f;
    const float* ab = att + b * VN;
    float acc = 0.f;
    for (int v = 0; v < VN; v++) acc += ab[v] * pb[v * NF];
    w34[(long long)b * DCTN * NF + t * NF + f] = acc;
}

// ---------------- x = concat(dct_in, dct_att); node-major f32 + feature-major bf16 ----
__global__ void build_x(const float* __restrict__ poses, const float* __restrict__ w34,
                        const float* __restrict__ dctm, float* __restrict__ x32,
                        ushort* __restrict__ xT16) {
    int idx = blockIdx.x * 256 + threadIdx.x;
    if (idx >= BATCH * NF * 68) return;
    int kk = idx % 68;
    int f = (idx / 68) % NF;
    int b = idx / (68 * NF);
    float acc = 0.f;
    if (kk < DCTN) {
        const float* pb = poses + (long long)b * POSE_ROWS * NF;
        #pragma unroll
        for (int t = 0; t < DCTN; t++) {
            int row = (t < KQ) ? (INN - KQ + t) : (INN - 1);
            acc += dctm[kk * DCTN + t] * pb[row * NF + f];
        }
    } else {
        int k2 = kk - DCTN;
        const float* wb = w34 + (long long)b * DCTN * NF + f;
        #pragma unroll
        for (int t = 0; t < DCTN; t++) acc += dctm[k2 * DCTN + t] * wb[t * NF];
    }
    long long R = (long long)b * NODEP + f;
    x32[R * 68 + kk] = acc;
    xT16[(long long)kk * RP + R] = f2bf(acc);
}

// ---------------- preds[b,t,f] = sum_k dct[k][10+t] * h32[(b*136+f)*68+k] ----------------
__global__ void idct_out(const float* __restrict__ h32, const float* __restrict__ dctm,
                         float* __restrict__ out) {
    int idx = blockIdx.x * 256 + threadIdx.x;
    if (idx >= BATCH * OUTN * NF) return;
    int f = idx % NF;
    int t = (idx / NF) % OUTN;
    int b = idx / (NF * OUTN);
    const float* yr = h32 + ((long long)b * NODEP + f) * 68;
    float acc = 0.f;
    #pragma unroll
    for (int k = 0; k < DCTN; k++) acc += dctm[k * DCTN + (KQ + t)] * yr[k];
    out[idx] = acc;
}

// ---------------- host ----------------
extern "C" void kernel_launch(void* const* d_in, const int* in_sizes, int n_in,
                              void* d_out, int out_size, void* d_ws, size_t ws_size,
                              hipStream_t stream) {
    const float* poses   = (const float*)d_in[0];
    const float* qw1     = (const float*)d_in[1];
    const float* qw2     = (const float*)d_in[2];
    const float* kw1     = (const float*)d_in[3];
    const float* kw2     = (const float*)d_in[4];
    const float* gc1_att = (const float*)d_in[5];
    const float* gc1_w   = (const float*)d_in[6];
    const float* gc1_b   = (const float*)d_in[7];
    const float* bn1_g   = (const float*)d_in[8];
    const float* bn1_b   = (const float*)d_in[9];
    const float* gcb_att = (const float*)d_in[10];
    const float* gcb_w   = (const float*)d_in[11];
    const float* gcb_b   = (const float*)d_in[12];
    const float* gcb_g   = (const float*)d_in[13];
    const float* gcb_beta= (const float*)d_in[14];
    const float* gc7_att = (const float*)d_in[15];
    const float* gc7_w   = (const float*)d_in[16];
    const float* gc7_b   = (const float*)d_in[17];
    float* out = (float*)d_out;
    float* w = (float*)d_ws;

    // ---- workspace layout (f32 units) ----
    float* dct   = w;                      // 1156 -> pad 1280
    float* att   = w + 1280;               // -> 23808
    float* w34   = w + 23808;              // -> 1198848
    float* x32   = w + 1198848;            // RP*68 -> 3566336
    float* h32   = w + 3566336;            // RP*68 -> 5933824
    float* qf    = w + 5933824;            // -> 6064896
    ushort* su   = (ushort*)(w + 6064896); // bf16 weight region
    ushort* WT1    = su;                   // 512*128   = 65536
    ushort* WTb    = su + 65536;           // 4*512*512 = 1048576
    ushort* WT7    = su + 1114112;         // 68*512    = 34816
    ushort* A16_1  = su + 1148928;         // 135*192   = 25920
    ushort* A16_B  = su + 1174848;         // 540*192   = 103680
    ushort* A16_7  = su + 1278528;         // 25920
    float* bnT   = w + 6717120;            // 10 * 69632 -> 7413440
    float* kf    = w + 7413440;            // 256*87*512 -> 18816704
    ushort* R2   = (ushort*)(w + 18816704);
    ushort* yT16  = R2;
    ushort* r1k16 = R2;                    // phase-A alias
    ushort* r1q16 = R2 + 11927552;
    ushort* R3   = (ushort*)(w + 27729600);
    ushort* hT16  = R3;
    ushort* pb16  = R3;                    // phase-A alias
    ushort* Wt1k  = R3 + 5013504;
    ushort* Wt1q  = R3 + 5439488;
    ushort* Wt2k  = R3 + 5865472;
    ushort* Wt2q  = R3 + 7176192;
    ushort* R4   = (ushort*)(w + 36642496);
    ushort* zN16  = R4;
    ushort* xT16  = R4;                    // alias (dead before zN16 written)
    ushort* z116  = R4 + 2367488;          // RP*80
    float* zpadf = w + 45555392;           // 128 f zero page
    const ushort* zpad = (const ushort*)zpadf;

    const int INF_RPB = 1 << 30;

    // ---- fused prep (one dispatch) ----
    prep_all<<<PB_DCT, 256, 0, stream>>>(
        poses, pb16, kw1, qw1, Wt1k, Wt1q, kw2, qw2, Wt2k, Wt2q,
        gc1_w, WT1, gcb_w, WTb, gc7_w, WT7,
        gc1_att, A16_1, gcb_att, A16_B, gc7_att, A16_7,
        bn1_g, bn1_b, gcb_g, gcb_beta, bnT, zpadf, dct);

    // ---- conv stack ----
    gemm2<128,64><<<dim3(8, 182, 1), 256, 0, stream>>>(pb16, Wt1k, zpad, 23296, 512, 832,
        91, 19584LL, 136LL, 0LL, 832LL, 0LL,
        (float*)nullptr, r1k16, 0LL, 512LL, 1LL, 1, nullptr, 0, nullptr, nullptr, 0, nullptr, nullptr);
    gemm2<128,64><<<dim3(8, 10, 1), 256, 0, stream>>>(pb16 + 110*136, Wt1q, zpad, 1280, 512, 832,
        5, 19584LL, 136LL, 0LL, 832LL, 0LL,
        (float*)nullptr, r1q16, 0LL, 512LL, 1LL, 1, nullptr, 0, nullptr, nullptr, 0, nullptr, nullptr);
    gemm2<128,64><<<dim3(8, 174, 1), 256, 0, stream>>>(r1k16, Wt2k, zpad, 22272, 512, 2560,
        87, 46592LL, 512LL, 0LL, 2560LL, 0LL,
        kf, (ushort*)nullptr, 0LL, 512LL, 1LL, 1, nullptr, 0, nullptr, nullptr, 0, nullptr, nullptr);
    gemm2<64,64><<<dim3(8, 4, 1), 256, 0, stream>>>(r1q16, Wt2q, zpad, 256, 512, 2560,
        INF_RPB, 0LL, 2560LL, 0LL, 2560LL, 0LL,
        qf, (ushort*)nullptr, 0LL, 512LL, 1LL, 1, nullptr, 0, nullptr, nullptr, 0, nullptr, nullptr);

    // ---- attention + x ----
    att_k<<<BATCH, 256, 0, stream>>>(kf, qf, att);
    weighted_k<<<dim3(DCTN, BATCH), 192, 0, stream>>>(poses, att, w34);
    build_x<<<(BATCH * NF * 68 + 255) / 256, 256, 0, stream>>>(poses, w34, dct, x32, xT16);

    // ---- gc1: mix then W(68->512) ----
    gemm2<64,64><<<dim3(3, 2, BATCH), 256, 0, stream>>>(xT16, A16_1, zpad, 68, 135, 192,
        INF_RPB, 0LL, (long long)RP, 136LL, 192LL, 0LL,
        (float*)nullptr, z116, 10880LL, 1LL, 80LL, 0, nullptr, 0, nullptr, nullptr, 0, nullptr, nullptr);
    gemm2<128,64><<<dim3(544, 4, 1), 256, 0, stream>>>(WT1, z116, zpad, 512, RP, 128,
        INF_RPB, 0LL, 128LL, 0LL, 80LL, 0LL,
        (float*)nullptr, yT16, 0LL, (long long)RP, 1LL, 0, gc1_b, 1, bnT, bnT + 69632, 1, nullptr, nullptr);

    // ---- residual GCN blocks ----
    for (int L = 0; L < 4; L++) {
        const ushort* min = (L & 1) ? hT16 : yT16;
        gemm2<64,64><<<dim3(3, 8, BATCH), 256, 0, stream>>>(min, A16_B + L*25920, zpad, 512, 135, 192,
            INF_RPB, 0LL, (long long)RP, 136LL, 192LL, 0LL,
            (float*)nullptr, zN16, 69632LL, 1LL, 512LL, 0, nullptr, 0, nullptr, nullptr, 0, nullptr, nullptr);
        gemm2<128,64><<<dim3(544, 4, 1), 256, 0, stream>>>(WTb + L*262144, zN16, zpad, 512, RP, 512,
            INF_RPB, 0LL, 512LL, 0LL, 512LL, 0LL,
            (float*)nullptr, (L & 1) ? yT16 : hT16, 0LL, (long long)RP, 1LL,
            0, gcb_b + L*512, 1, bnT + (1 + L) * 139264, bnT + (1 + L) * 139264 + 69632, 1,
            (L & 1) ? yT16 : (const ushort*)nullptr, nullptr);
    }

    // ---- gc7: mix then W(512->68) + bias + x residual ----
    gemm2<64,64><<<dim3(3, 8, BATCH), 256, 0, stream>>>(yT16, A16_7, zpad, 512, 135, 192,
        INF_RPB, 0LL, (long long)RP, 136LL, 192LL, 0LL,
        (float*)nullptr, zN16, 69632LL, 1LL, 512LL, 0, nullptr, 0, nullptr, nullptr, 0, nullptr, nullptr);
    gemm2<64,64><<<dim3(2, 544, 1), 256, 0, stream>>>(zN16, WT7, zpad, RP, 68, 512,
        INF_RPB, 0LL, 512LL, 0LL, 512LL, 0LL,
        h32, (ushort*)nullptr, 0LL, 68LL, 1LL, 0, gc7_b, 2, nullptr, nullptr, 0, nullptr, x32);

    idct_out<<<(BATCH * OUTN * NF + 255) / 256, 256, 0, stream>>>(h32, dct, out);
}